// Round 13
// baseline (176.595 us; speedup 1.0000x reference)
//
#include <hip/hip_runtime.h>
#include <hip/hip_bf16.h>
#include <stdint.h>

#define Bsz  2
#define Tseq 2048
#define Dmod 1024
#define Hn   16
#define DHd  64

typedef short bf16x8 __attribute__((ext_vector_type(8)));
typedef float f32x4 __attribute__((ext_vector_type(4)));

__device__ __forceinline__ float bf2f(unsigned short u) {
  union { unsigned int i; float f; } v; v.i = ((unsigned int)u) << 16; return v.f;
}
__device__ __forceinline__ unsigned short f2bf(float f) {
  union { float f; unsigned int i; } v; v.f = f;
  unsigned int r = (v.i + 0x7fffu + ((v.i >> 16) & 1u)) >> 16;
  return (unsigned short)r;
}
__device__ __forceinline__ unsigned int pk_bf16(float a, float b) {
  union { __hip_bfloat162 h; unsigned int u; } u2;
  u2.h = __float22bfloat162_rn(make_float2(a, b));
  return u2.u;
}
// async global->LDS, 16B per lane; LDS dest = wave-uniform base + lane*16
__device__ __forceinline__ void gl_lds16(const unsigned short* g, unsigned short* l) {
  __builtin_amdgcn_global_load_lds(
      (const __attribute__((address_space(1))) void*)g,
      (__attribute__((address_space(3))) void*)l, 16, 0, 0);
}

#define QSCALE 0.1803368801f   // 0.125 * log2(e), folded into Q at GEMM1 epilogue

// ---------------- fused prep: cast x -> bf16, transpose+cast w_qkv & w_out ----------------
// R18: float4 weight reads + uint4 transposed stores.
__global__ __launch_bounds__(256) void prep(const float* __restrict__ x,
                                            const float* __restrict__ w_qkv,
                                            const float* __restrict__ w_out,
                                            unsigned short* __restrict__ xb,
                                            unsigned short* __restrict__ wqkvT,
                                            unsigned short* __restrict__ woutT) {
  __shared__ unsigned short tile[64][65];
  const int blk = blockIdx.x;
  if (blk < 2048) {
    int idx = blk * 2048 + threadIdx.x * 8;
    float4 a = *(const float4*)&x[idx];
    float4 b = *(const float4*)&x[idx + 4];
    unsigned short o[8];
    o[0] = f2bf(a.x); o[1] = f2bf(a.y); o[2] = f2bf(a.z); o[3] = f2bf(a.w);
    o[4] = f2bf(b.x); o[5] = f2bf(b.y); o[6] = f2bf(b.z); o[7] = f2bf(b.w);
    *(uint4*)&xb[idx] = *(const uint4*)o;
    return;
  }
  const float* in;
  unsigned short* out;
  int K = 1024, N, k0, n0;
  if (blk < 2048 + 768) {
    int t = blk - 2048;
    in = w_qkv; out = wqkvT; N = 3072;
    n0 = (t % 48) * 64; k0 = (t / 48) * 64;
  } else {
    int t = blk - 2816;
    in = w_out; out = woutT; N = 1024;
    n0 = (t % 16) * 64; k0 = (t / 16) * 64;
  }
  for (int i = threadIdx.x * 4; i < 4096; i += 1024) {
    int r = i >> 6, c = i & 63;
    float4 f = *(const float4*)&in[(size_t)(k0 + r) * N + n0 + c];
    tile[r][c]     = f2bf(f.x);
    tile[r][c + 1] = f2bf(f.y);
    tile[r][c + 2] = f2bf(f.z);
    tile[r][c + 3] = f2bf(f.w);
  }
  __syncthreads();
  for (int i = threadIdx.x * 8; i < 4096; i += 2048) {
    int r = i >> 6, c = i & 63;
    unsigned short o[8];
#pragma unroll
    for (int j = 0; j < 8; j++) o[j] = tile[c + j][r];
    *(uint4*)&out[(size_t)(n0 + r) * K + k0 + c] = *(const uint4*)o;
  }
}

// ---------------- GEMM1: 128x128, BK=32, 3-buffer prefetch-2, counted vmcnt ----------------
// R20: depth-2 DMA pipeline. Data read at iter k was DMA'd at k-2; iter k-1's
// s_waitcnt vmcnt(4) certified it complete BEFORE that wave reached the k-1 barrier,
// so the k-barrier never drains the newest 4 in-flight DMAs (never vmcnt(0) in the
// main loop -- AITER pattern). Buffer (k%3) is only overwritten by DMA issued at
// k+1, after the iter-k rendezvous -> race-free. Tail (last 2 iters): vmcnt(0).
// TILE NOTE (R10/R17): 128x128 = 16 MFMA/barrier is this structure's optimum; both
// 128x64 and 64->128 regressed. mode 0 scatters Q(xQSCALE)/K/V^T(sigma-permuted).
template<int MT, int NT>
__global__ __launch_bounds__(256) void gemm_bt(const unsigned short* __restrict__ A,
                                               const unsigned short* __restrict__ Bt,
                                               const float* __restrict__ bias,
                                               int M, int N, int K, int mode,
                                               float* __restrict__ outF,
                                               unsigned short* __restrict__ out0,
                                               unsigned short* __restrict__ out1,
                                               unsigned short* __restrict__ out2) {
  constexpr int IT = MT / 32;   // i-tiles per wave
  constexpr int JT = NT / 32;   // j-tiles per wave
  constexpr int AP = MT / 64;   // A DMA insts per wave per kt
  constexpr int BP = NT / 64;   // B DMA insts per wave per kt
  __shared__ unsigned short As[3][MT * 32];
  __shared__ unsigned short Bs[3][NT * 32];
  const int tid  = threadIdx.x;
  const int lane = tid & 63;
  const int w    = tid >> 6;
  const int m0   = blockIdx.x * MT;
  const int n0   = blockIdx.y * NT;
  const int wr   = (w >> 1) * (MT / 2);
  const int wc   = (w & 1) * (NT / 2);

  f32x4 acc[IT][JT];
  for (int i = 0; i < IT; i++)
    for (int j = 0; j < JT; j++)
      for (int v = 0; v < 4; v++) acc[i][j][v] = 0.0f;

  const int l16  = lane & 15;
  const int g    = lane >> 4;
  const int fkey = (l16 & 3) ^ ((l16 >> 2) & 3);          // fragment swizzle key

  const int csw = (((lane & 3) ^ ((lane >> 2) & 3) ^ ((lane >> 4) & 3)) & 3) * 8;
  const unsigned short* ga[AP];
  const unsigned short* gb[BP];
  unsigned short* la[3][AP];
  unsigned short* lb[3][BP];
#pragma unroll
  for (int p = 0; p < AP; p++) {
    int r = (MT / 4) * w + 16 * p + (lane >> 2);
    ga[p] = A + (size_t)(m0 + r) * K + csw;
#pragma unroll
    for (int b = 0; b < 3; b++) la[b][p] = &As[b][((MT / 4) * w + 16 * p) * 32];
  }
#pragma unroll
  for (int p = 0; p < BP; p++) {
    int r = (NT / 4) * w + 16 * p + (lane >> 2);
    gb[p] = Bt + (size_t)(n0 + r) * K + csw;
#pragma unroll
    for (int b = 0; b < 3; b++) lb[b][p] = &Bs[b][((NT / 4) * w + 16 * p) * 32];
  }

  // prologue: stage kt=0 -> buf0, kt=32 -> buf1; wait only buf0 (vmcnt(4))
#pragma unroll
  for (int p = 0; p < AP; p++) gl_lds16(ga[p], la[0][p]);
#pragma unroll
  for (int p = 0; p < BP; p++) gl_lds16(gb[p], lb[0][p]);
#pragma unroll
  for (int p = 0; p < AP; p++) gl_lds16(ga[p] + 32, la[1][p]);
#pragma unroll
  for (int p = 0; p < BP; p++) gl_lds16(gb[p] + 32, lb[1][p]);
  asm volatile("s_waitcnt vmcnt(4)" ::: "memory");
  __builtin_amdgcn_sched_barrier(0);
  __builtin_amdgcn_s_barrier();

  int cur = 0;
  for (int kt = 0; kt < K; kt += 32) {
    const int pre = (cur == 0) ? 2 : cur - 1;   // (cur+2)%3
    if (kt + 64 < K) {   // DMA prefetch the (k+2) slab
#pragma unroll
      for (int p = 0; p < AP; p++) gl_lds16(ga[p] + kt + 64, la[pre][p]);
#pragma unroll
      for (int p = 0; p < BP; p++) gl_lds16(gb[p] + kt + 64, lb[pre][p]);
    }
    bf16x8 af[IT], bf[JT];
#pragma unroll
    for (int i = 0; i < IT; i++)
      af[i] = *(const bf16x8*)&As[cur][(wr + i * 16 + l16) * 32 + ((g ^ fkey) * 8)];
#pragma unroll
    for (int j = 0; j < JT; j++)
      bf[j] = *(const bf16x8*)&Bs[cur][(wc + j * 16 + l16) * 32 + ((g ^ fkey) * 8)];
#pragma unroll
    for (int i = 0; i < IT; i++)
#pragma unroll
      for (int j = 0; j < JT; j++)
        acc[i][j] = __builtin_amdgcn_mfma_f32_16x16x32_bf16(af[i], bf[j], acc[i][j], 0, 0, 0);
    // counted wait: next iter's buffer (issued last iter) must be done; the 4 DMAs
    // issued THIS iter (for k+2) stay in flight across the barrier.
    if (kt + 64 < K) {
      asm volatile("s_waitcnt vmcnt(4)" ::: "memory");
    } else {
      asm volatile("s_waitcnt vmcnt(0)" ::: "memory");
    }
    __builtin_amdgcn_sched_barrier(0);
    __builtin_amdgcn_s_barrier();
    cur = (cur == 2) ? 0 : cur + 1;
  }

  const int q4 = g * 4;
#pragma unroll
  for (int i = 0; i < IT; i++)
#pragma unroll
    for (int j = 0; j < JT; j++) {
      const int mbase = m0 + wr + i * 16 + q4;
      const int n = n0 + wc + j * 16 + l16;
      float vals[4];
#pragma unroll
      for (int v = 0; v < 4; v++) vals[v] = acc[i][j][v] + bias[n];
      if (mode == 1) {
#pragma unroll
        for (int v = 0; v < 4; v++)
          outF[(size_t)(mbase + v) * N + n] = vals[v];
      } else {
        const int which = n >> 10;
        const int rem = n & 1023;
        const int h = rem >> 6, dd = rem & 63;
        const int b = mbase >> 11, t = mbase & 2047;
        if (which == 2) {
          uint2 uu;
          uu.x = pk_bf16(vals[0], vals[1]);
          uu.y = pk_bf16(vals[2], vals[3]);
          // sigma = pi^-1: permute t within its 64-block so attn's PV A-fragment
          // (built lane-locally from QK^T registers) contracts matching k-positions.
          const int t2 = (t & ~63) | (t & 32) | (((t >> 2) & 3) << 3) | (((t >> 4) & 1) << 2);
          *(uint2*)&out2[((size_t)((b * Hn + h) * DHd + dd)) * Tseq + t2] = uu;
        } else if (which == 0) {
#pragma unroll
          for (int v = 0; v < 4; v++)
            out0[(size_t)((b * Hn + h) * Tseq + t + v) * DHd + dd] = f2bf(vals[v] * QSCALE);
        } else {
#pragma unroll
          for (int v = 0; v < 4; v++)
            out1[(size_t)((b * Hn + h) * Tseq + t + v) * DHd + dd] = f2bf(vals[v]);
        }
      }
    }
}

// ---------------- GEMM2: 64x64 tile, BK=64 (R19, kept) ----------------
__global__ __launch_bounds__(256) void gemm_bt2(const unsigned short* __restrict__ A,
                                                const unsigned short* __restrict__ Bt,
                                                const float* __restrict__ bias,
                                                int M, int N, int K,
                                                float* __restrict__ outF) {
  __shared__ unsigned short As[2][64 * 64];
  __shared__ unsigned short Bs[2][64 * 64];
  const int tid  = threadIdx.x;
  const int lane = tid & 63;
  const int w    = tid >> 6;
  const int m0   = blockIdx.x * 64;
  const int n0   = blockIdx.y * 64;
  const int wr   = (w >> 1) * 32;
  const int wc   = (w & 1) * 32;
  const int l16  = lane & 15;
  const int g    = lane >> 4;
  const int swz  = l16 & 7;

  f32x4 acc[2][2];
  for (int i = 0; i < 2; i++)
    for (int j = 0; j < 2; j++)
      for (int v = 0; v < 4; v++) acc[i][j][v] = 0.f;

  const int csw = (((lane & 7) ^ (lane >> 3)) & 7) * 8;
  const unsigned short* ga[2];
  const unsigned short* gb[2];
  unsigned short* la[2][2];
  unsigned short* lb[2][2];
#pragma unroll
  for (int p = 0; p < 2; p++) {
    const int r = 16 * w + 8 * p + (lane >> 3);
    ga[p] = A  + (size_t)(m0 + r) * K + csw;
    gb[p] = Bt + (size_t)(n0 + r) * K + csw;
    la[0][p] = &As[0][(16 * w + 8 * p) * 64];
    la[1][p] = &As[1][(16 * w + 8 * p) * 64];
    lb[0][p] = &Bs[0][(16 * w + 8 * p) * 64];
    lb[1][p] = &Bs[1][(16 * w + 8 * p) * 64];
  }

#pragma unroll
  for (int p = 0; p < 2; p++) { gl_lds16(ga[p], la[0][p]); gl_lds16(gb[p], lb[0][p]); }
  __syncthreads();

  for (int kt = 0; kt < K; kt += 64) {
    const int cur = (kt >> 6) & 1, nxt = cur ^ 1;
    if (kt + 64 < K) {
#pragma unroll
      for (int p = 0; p < 2; p++) {
        gl_lds16(ga[p] + kt + 64, la[nxt][p]);
        gl_lds16(gb[p] + kt + 64, lb[nxt][p]);
      }
    }
#pragma unroll
    for (int ks = 0; ks < 2; ks++) {   // k-slice: logical col-block = 4*ks+g
      bf16x8 af[2], bf[2];
#pragma unroll
      for (int i = 0; i < 2; i++)
        af[i] = *(const bf16x8*)&As[cur][(wr + i * 16 + l16) * 64 + (((ks * 4 + g) ^ swz) * 8)];
#pragma unroll
      for (int j = 0; j < 2; j++)
        bf[j] = *(const bf16x8*)&Bs[cur][(wc + j * 16 + l16) * 64 + (((ks * 4 + g) ^ swz) * 8)];
#pragma unroll
      for (int i = 0; i < 2; i++)
#pragma unroll
        for (int j = 0; j < 2; j++)
          acc[i][j] = __builtin_amdgcn_mfma_f32_16x16x32_bf16(af[i], bf[j], acc[i][j], 0, 0, 0);
    }
    __syncthreads();
  }

  const int q4 = g * 4;
#pragma unroll
  for (int i = 0; i < 2; i++)
#pragma unroll
    for (int j = 0; j < 2; j++) {
      const int mbase = m0 + wr + i * 16 + q4;
      const int n = n0 + wc + j * 16 + l16;
#pragma unroll
      for (int v = 0; v < 4; v++)
        outF[(size_t)(mbase + v) * N + n] = acc[i][j][v] + bias[n];
    }
}

// ---------------- MFMA causal flash attention, fixed-reference softmax ----------------
// R13 core (best measured): 4 waves x 16 q-rows, grid 32x32 (bh=blockIdx.x so a CU's
// 4 co-resident blocks share one head's K/V stream -- do NOT change this decode),
// register-resident P via pi k-permutation, LDS 32KB, bank conflicts = 0.
// R16: l-sum via MFMA. R18: s_setprio(1) around MFMA clusters.
__global__ __launch_bounds__(256, 4) void attn_mfma(const unsigned short* __restrict__ Qb,
                                                    const unsigned short* __restrict__ Kb,
                                                    const unsigned short* __restrict__ Vtg,
                                                    unsigned short* __restrict__ O) {
  __shared__ unsigned short Ks[2][64 * 64];   // [j][d], swizzled
  __shared__ unsigned short Vs[2][64 * 64];   // [d][j], swizzled, j pre-permuted by pi

  const int tid  = threadIdx.x;
  const int lane = tid & 63;
  const int w    = tid >> 6;
  const int g    = lane >> 4;
  const int l16  = lane & 15;
  const int bh   = blockIdx.x;
  const int tile = (int)gridDim.y - 1 - (int)blockIdx.y;   // heavy blocks first
  const int q0w  = tile * 64 + w * 16;

  const unsigned short* Qp = Qb  + (size_t)bh * Tseq * DHd;
  const unsigned short* Kp = Kb  + (size_t)bh * Tseq * DHd;
  const unsigned short* Vp = Vtg + (size_t)bh * DHd * Tseq;

  bf16x8 qf[2];
#pragma unroll
  for (int ks = 0; ks < 2; ks++)
    qf[ks] = *(const bf16x8*)&Qp[(size_t)(q0w + l16) * DHd + ks * 32 + g * 8];

  f32x4 Oacc[4];
#pragma unroll
  for (int dt = 0; dt < 4; dt++)
#pragma unroll
    for (int v = 0; v < 4; v++) Oacc[dt][v] = 0.f;

  const f32x4 FZ = {0.f, 0.f, 0.f, 0.f};     // persistent zero C-operand
  f32x4 Lacc = {0.f, 0.f, 0.f, 0.f};         // l-sums via MFMA: Lacc[v] = l[q=4g+v]
  bf16x8 onef;
  {
    union { unsigned short s[8]; bf16x8 v8; } ou;
#pragma unroll
    for (int m = 0; m < 8; m++) ou.s[m] = 0x3F80;   // bf16 1.0
    onef = ou.v8;
  }
  const int swz = l16 & 7;

  const int csw = (((lane & 7) ^ (lane >> 3)) & 7) * 8;
  const unsigned short* KgB = Kp + (size_t)(16 * w + (lane >> 3)) * DHd + csw;
  const unsigned short* VgB = Vp + (size_t)(16 * w + (lane >> 3)) * Tseq + csw;
  unsigned short* KsW[2] = { &Ks[0][16 * w * 64], &Ks[1][16 * w * 64] };
  unsigned short* VsW[2] = { &Vs[0][16 * w * 64], &Vs[1][16 * w * 64] };

  gl_lds16(KgB,             KsW[0]);
  gl_lds16(KgB + 8 * DHd,   KsW[0] + 8 * 64);
  gl_lds16(VgB,             VsW[0]);
  gl_lds16(VgB + 8 * Tseq,  VsW[0] + 8 * 64);
  __syncthreads();

  for (int c = 0; c <= tile; c++) {
    const int cur = c & 1, nxt = cur ^ 1;
    if (c < tile) {
      const size_t ko = (size_t)(c + 1) * 64 * DHd;
      const int    vo = (c + 1) * 64;
      gl_lds16(KgB + ko,            KsW[nxt]);
      gl_lds16(KgB + ko + 8 * DHd,  KsW[nxt] + 8 * 64);
      gl_lds16(VgB + vo,            VsW[nxt]);
      gl_lds16(VgB + vo + 8 * Tseq, VsW[nxt] + 8 * 64);
    }

    f32x4 st[4];
    {   // ks = 0: zero C-operand (no per-iter acc init)
      bf16x8 kf[4];
#pragma unroll
      for (int mt = 0; mt < 4; mt++)
        kf[mt] = *(const bf16x8*)&Ks[cur][(16 * mt + l16) * 64 + ((g ^ swz) * 8)];
      __builtin_amdgcn_s_setprio(1);
#pragma unroll
      for (int mt = 0; mt < 4; mt++)
        st[mt] = __builtin_amdgcn_mfma_f32_16x16x32_bf16(kf[mt], qf[0], FZ, 0, 0, 0);
      __builtin_amdgcn_s_setprio(0);
    }
    {   // ks = 1
      bf16x8 kf[4];
#pragma unroll
      for (int mt = 0; mt < 4; mt++)
        kf[mt] = *(const bf16x8*)&Ks[cur][(16 * mt + l16) * 64 + (((4 + g) ^ swz) * 8)];
      __builtin_amdgcn_s_setprio(1);
#pragma unroll
      for (int mt = 0; mt < 4; mt++)
        st[mt] = __builtin_amdgcn_mfma_f32_16x16x32_bf16(kf[mt], qf[1], st[mt], 0, 0, 0);
      __builtin_amdgcn_s_setprio(0);
    }

    if (c == tile) {
      const int qg = q0w + l16;
#pragma unroll
      for (int mt = 0; mt < 4; mt++)
#pragma unroll
        for (int v = 0; v < 4; v++)
          if ((c * 64 + 16 * mt + 4 * g + v) > qg) st[mt][v] = -1e30f;
    }

    // softmax + in-register PV A-fragment (pi-permuted k)
    unsigned int pw[2][4];
#pragma unroll
    for (int mt = 0; mt < 4; mt++) {
      float p[4];
#pragma unroll
      for (int v = 0; v < 4; v++) p[v] = __builtin_exp2f(st[mt][v]);
      pw[mt >> 1][(mt & 1) * 2 + 0] = pk_bf16(p[0], p[1]);
      pw[mt >> 1][(mt & 1) * 2 + 1] = pk_bf16(p[2], p[3]);
    }

#pragma unroll
    for (int ks = 0; ks < 2; ks++) {
      union { unsigned int u[4]; bf16x8 v8; } pu;
#pragma unroll
      for (int m = 0; m < 4; m++) pu.u[m] = pw[ks][m];
      const bf16x8 pf = pu.v8;
      bf16x8 vf[4];
#pragma unroll
      for (int dt = 0; dt < 4; dt++)
        vf[dt] = *(const bf16x8*)&Vs[cur][(16 * dt + l16) * 64 + (((4 * ks + g) ^ swz) * 8)];
      __builtin_amdgcn_s_setprio(1);
      Lacc = __builtin_amdgcn_mfma_f32_16x16x32_bf16(pf, onef, Lacc, 0, 0, 0);
#pragma unroll
      for (int dt = 0; dt < 4; dt++)
        Oacc[dt] = __builtin_amdgcn_mfma_f32_16x16x32_bf16(pf, vf[dt], Oacc[dt], 0, 0, 0);
      __builtin_amdgcn_s_setprio(0);
    }

    __syncthreads();
  }

  const float i0 = 1.f / Lacc[0], i1 = 1.f / Lacc[1];
  const float i2 = 1.f / Lacc[2], i3 = 1.f / Lacc[3];
  const int b = bh >> 4, h = bh & 15;
#pragma unroll
  for (int dt = 0; dt < 4; dt++) {
    const int d = h * DHd + 16 * dt + l16;
    const size_t r0 = (size_t)(b * Tseq + q0w + 4 * g) * Dmod + d;
    O[r0]            = f2bf(Oacc[dt][0] * i0);
    O[r0 + Dmod]     = f2bf(Oacc[dt][1] * i1);
    O[r0 + 2 * Dmod] = f2bf(Oacc[dt][2] * i2);
    O[r0 + 3 * Dmod] = f2bf(Oacc[dt][3] * i3);
  }
}

extern "C" void kernel_launch(void* const* d_in, const int* in_sizes, int n_in,
                              void* d_out, int out_size, void* d_ws, size_t ws_size,
                              hipStream_t stream) {
  (void)in_sizes; (void)n_in; (void)out_size; (void)ws_size;
  const float* x     = (const float*)d_in[0];  // [B,T,D]   fp32
  const float* w_qkv = (const float*)d_in[1];  // [D,3D]    fp32
  const float* b_qkv = (const float*)d_in[2];  // [3D]      fp32
  const float* w_out = (const float*)d_in[3];  // [D,D]     fp32
  const float* b_out = (const float*)d_in[4];  // [D]       fp32
  float* out = (float*)d_out;                  // [B,T,D]   fp32

  unsigned short* ws    = (unsigned short*)d_ws;
  unsigned short* xb    = ws;                            // [B*T, D] bf16, reused as Ob
  unsigned short* wqkvT = xb    + (size_t)4194304;       // [3D][D]
  unsigned short* woutT = wqkvT + (size_t)3072 * 1024;   // [D][D]
  unsigned short* Qb    = woutT + (size_t)1024 * 1024;   // [B,H,T,DH] (pre-scaled)
  unsigned short* Kb    = Qb + (size_t)4194304;          // [B,H,T,DH]
  unsigned short* Vt    = Kb + (size_t)4194304;          // [B,H,DH,T] (transposed, pi-permuted)
  unsigned short* Ob    = xb;  // reuse: xb dead after GEMM1

  prep<<<3072, 256, 0, stream>>>(x, w_qkv, w_out, xb, wqkvT, woutT);
  // R20: GEMM1 with 3-buffer depth-2 prefetch + counted vmcnt(4) at the barrier
  gemm_bt<128, 128><<<dim3(32, 24), 256, 0, stream>>>(xb, wqkvT, b_qkv, 4096, 3072, 1024, 0,
                                                      nullptr, Qb, Kb, Vt);
  attn_mfma<<<dim3(32, 32), 256, 0, stream>>>(Qb, Kb, Vt, Ob);
  gemm_bt2<<<dim3(64, 16), 256, 0, stream>>>(Ob, woutT, b_out, 4096, 1024, 1024, out);
}

// Round 14
// 173.934 us; speedup vs baseline: 1.0153x; 1.0153x over previous
//
#include <hip/hip_runtime.h>
#include <hip/hip_bf16.h>
#include <stdint.h>

#define Bsz  2
#define Tseq 2048
#define Dmod 1024
#define Hn   16
#define DHd  64

typedef short bf16x8 __attribute__((ext_vector_type(8)));
typedef float f32x4 __attribute__((ext_vector_type(4)));

__device__ __forceinline__ float bf2f(unsigned short u) {
  union { unsigned int i; float f; } v; v.i = ((unsigned int)u) << 16; return v.f;
}
__device__ __forceinline__ unsigned short f2bf(float f) {
  union { float f; unsigned int i; } v; v.f = f;
  unsigned int r = (v.i + 0x7fffu + ((v.i >> 16) & 1u)) >> 16;
  return (unsigned short)r;
}
__device__ __forceinline__ unsigned int pk_bf16(float a, float b) {
  union { __hip_bfloat162 h; unsigned int u; } u2;
  u2.h = __float22bfloat162_rn(make_float2(a, b));
  return u2.u;
}
// async global->LDS, 16B per lane; LDS dest = wave-uniform base + lane*16
__device__ __forceinline__ void gl_lds16(const unsigned short* g, unsigned short* l) {
  __builtin_amdgcn_global_load_lds(
      (const __attribute__((address_space(1))) void*)g,
      (__attribute__((address_space(3))) void*)l, 16, 0, 0);
}

#define QSCALE 0.1803368801f   // 0.125 * log2(e), folded into Q at GEMM1 epilogue

// ---------------- fused prep: cast x -> bf16, transpose+cast w_qkv & w_out ----------------
// R18: float4 weight reads + uint4 transposed stores.
__global__ __launch_bounds__(256) void prep(const float* __restrict__ x,
                                            const float* __restrict__ w_qkv,
                                            const float* __restrict__ w_out,
                                            unsigned short* __restrict__ xb,
                                            unsigned short* __restrict__ wqkvT,
                                            unsigned short* __restrict__ woutT) {
  __shared__ unsigned short tile[64][65];
  const int blk = blockIdx.x;
  if (blk < 2048) {
    int idx = blk * 2048 + threadIdx.x * 8;
    float4 a = *(const float4*)&x[idx];
    float4 b = *(const float4*)&x[idx + 4];
    unsigned short o[8];
    o[0] = f2bf(a.x); o[1] = f2bf(a.y); o[2] = f2bf(a.z); o[3] = f2bf(a.w);
    o[4] = f2bf(b.x); o[5] = f2bf(b.y); o[6] = f2bf(b.z); o[7] = f2bf(b.w);
    *(uint4*)&xb[idx] = *(const uint4*)o;
    return;
  }
  const float* in;
  unsigned short* out;
  int K = 1024, N, k0, n0;
  if (blk < 2048 + 768) {
    int t = blk - 2048;
    in = w_qkv; out = wqkvT; N = 3072;
    n0 = (t % 48) * 64; k0 = (t / 48) * 64;
  } else {
    int t = blk - 2816;
    in = w_out; out = woutT; N = 1024;
    n0 = (t % 16) * 64; k0 = (t / 16) * 64;
  }
  for (int i = threadIdx.x * 4; i < 4096; i += 1024) {
    int r = i >> 6, c = i & 63;
    float4 f = *(const float4*)&in[(size_t)(k0 + r) * N + n0 + c];
    tile[r][c]     = f2bf(f.x);
    tile[r][c + 1] = f2bf(f.y);
    tile[r][c + 2] = f2bf(f.z);
    tile[r][c + 3] = f2bf(f.w);
  }
  __syncthreads();
  for (int i = threadIdx.x * 8; i < 4096; i += 2048) {
    int r = i >> 6, c = i & 63;
    unsigned short o[8];
#pragma unroll
    for (int j = 0; j < 8; j++) o[j] = tile[c + j][r];
    *(uint4*)&out[(size_t)(n0 + r) * K + k0 + c] = *(const uint4*)o;
  }
}

// ---------------- GEMM (BK=32 template, used by GEMM1): C = A Bt^T + bias ----------------
// STRUCTURE NOTE (R10/R17/R20 measured): 128x128, BK=32, 2-buffer, one drain-barrier
// per K-iter is this template's LOCAL OPTIMUM. Tried and regressed: 128x64 tile
// (R17), 64->128 GEMM2 (R10), 3-buffer depth-2 counted-vmcnt (R20: ~42 -> 46.6us,
// the m139 null replicates negative). Cross-run GEMM1 timings vary 43-54us with
// identical source (rule #19 co-compile + chip variance) -- only compare within-run.
// mode 0: scatter bf16 to Q (xQSCALE) / K [B,H,T,DH], V^T [B,H,DH,T] (sigma-permuted);
// mode 1: fp32.
template<int MT, int NT>
__global__ __launch_bounds__(256) void gemm_bt(const unsigned short* __restrict__ A,
                                               const unsigned short* __restrict__ Bt,
                                               const float* __restrict__ bias,
                                               int M, int N, int K, int mode,
                                               float* __restrict__ outF,
                                               unsigned short* __restrict__ out0,
                                               unsigned short* __restrict__ out1,
                                               unsigned short* __restrict__ out2) {
  constexpr int IT = MT / 32;   // i-tiles per wave
  constexpr int JT = NT / 32;   // j-tiles per wave
  constexpr int AP = MT / 64;   // A DMA insts per wave per kt
  constexpr int BP = NT / 64;   // B DMA insts per wave per kt
  __shared__ unsigned short As[2][MT * 32];
  __shared__ unsigned short Bs[2][NT * 32];
  const int tid  = threadIdx.x;
  const int lane = tid & 63;
  const int w    = tid >> 6;
  const int m0   = blockIdx.x * MT;
  const int n0   = blockIdx.y * NT;
  const int wr   = (w >> 1) * (MT / 2);
  const int wc   = (w & 1) * (NT / 2);

  f32x4 acc[IT][JT];
  for (int i = 0; i < IT; i++)
    for (int j = 0; j < JT; j++)
      for (int v = 0; v < 4; v++) acc[i][j][v] = 0.0f;

  const int l16  = lane & 15;
  const int g    = lane >> 4;
  const int fkey = (l16 & 3) ^ ((l16 >> 2) & 3);          // fragment swizzle key

  const int csw = (((lane & 3) ^ ((lane >> 2) & 3) ^ ((lane >> 4) & 3)) & 3) * 8;
  const unsigned short* ga[AP];
  const unsigned short* gb[BP];
  unsigned short* la[2][AP];
  unsigned short* lb[2][BP];
#pragma unroll
  for (int p = 0; p < AP; p++) {
    int r = (MT / 4) * w + 16 * p + (lane >> 2);
    ga[p] = A + (size_t)(m0 + r) * K + csw;
    la[0][p] = &As[0][((MT / 4) * w + 16 * p) * 32];
    la[1][p] = &As[1][((MT / 4) * w + 16 * p) * 32];
  }
#pragma unroll
  for (int p = 0; p < BP; p++) {
    int r = (NT / 4) * w + 16 * p + (lane >> 2);
    gb[p] = Bt + (size_t)(n0 + r) * K + csw;
    lb[0][p] = &Bs[0][((NT / 4) * w + 16 * p) * 32];
    lb[1][p] = &Bs[1][((NT / 4) * w + 16 * p) * 32];
  }

  // stage kt=0 -> buf 0
#pragma unroll
  for (int p = 0; p < AP; p++) gl_lds16(ga[p], la[0][p]);
#pragma unroll
  for (int p = 0; p < BP; p++) gl_lds16(gb[p], lb[0][p]);
  __syncthreads();

  for (int kt = 0; kt < K; kt += 32) {
    const int cur = (kt >> 5) & 1, nxt = cur ^ 1;
    if (kt + 32 < K) {   // DMA prefetch next 32-slab into the other buffer
#pragma unroll
      for (int p = 0; p < AP; p++) gl_lds16(ga[p] + kt + 32, la[nxt][p]);
#pragma unroll
      for (int p = 0; p < BP; p++) gl_lds16(gb[p] + kt + 32, lb[nxt][p]);
    }
    bf16x8 af[IT], bf[JT];
#pragma unroll
    for (int i = 0; i < IT; i++)
      af[i] = *(const bf16x8*)&As[cur][(wr + i * 16 + l16) * 32 + ((g ^ fkey) * 8)];
#pragma unroll
    for (int j = 0; j < JT; j++)
      bf[j] = *(const bf16x8*)&Bs[cur][(wc + j * 16 + l16) * 32 + ((g ^ fkey) * 8)];
#pragma unroll
    for (int i = 0; i < IT; i++)
#pragma unroll
      for (int j = 0; j < JT; j++)
        acc[i][j] = __builtin_amdgcn_mfma_f32_16x16x32_bf16(af[i], bf[j], acc[i][j], 0, 0, 0);
    __syncthreads();  // drains DMA; protects buffer swap
  }

  const int q4 = g * 4;
#pragma unroll
  for (int i = 0; i < IT; i++)
#pragma unroll
    for (int j = 0; j < JT; j++) {
      const int mbase = m0 + wr + i * 16 + q4;
      const int n = n0 + wc + j * 16 + l16;
      float vals[4];
#pragma unroll
      for (int v = 0; v < 4; v++) vals[v] = acc[i][j][v] + bias[n];
      if (mode == 1) {
#pragma unroll
        for (int v = 0; v < 4; v++)
          outF[(size_t)(mbase + v) * N + n] = vals[v];
      } else {
        const int which = n >> 10;
        const int rem = n & 1023;
        const int h = rem >> 6, dd = rem & 63;
        const int b = mbase >> 11, t = mbase & 2047;
        if (which == 2) {
          uint2 uu;
          uu.x = pk_bf16(vals[0], vals[1]);
          uu.y = pk_bf16(vals[2], vals[3]);
          // sigma = pi^-1: permute t within its 64-block so attn's PV A-fragment
          // (built lane-locally from QK^T registers) contracts matching k-positions.
          const int t2 = (t & ~63) | (t & 32) | (((t >> 2) & 3) << 3) | (((t >> 4) & 1) << 2);
          *(uint2*)&out2[((size_t)((b * Hn + h) * DHd + dd)) * Tseq + t2] = uu;
        } else if (which == 0) {
#pragma unroll
          for (int v = 0; v < 4; v++)
            out0[(size_t)((b * Hn + h) * Tseq + t + v) * DHd + dd] = f2bf(vals[v] * QSCALE);
        } else {
#pragma unroll
          for (int v = 0; v < 4; v++)
            out1[(size_t)((b * Hn + h) * Tseq + t + v) * DHd + dd] = f2bf(vals[v]);
        }
      }
    }
}

// ---------------- GEMM2: 64x64 tile, BK=64 (R19) ----------------
// Same 2-barrier dbuf structure but 64-col LDS rows: barriers halve (32->16),
// MFMA/barrier doubles (4->8), LDS 32KB keeps 4 blocks/CU. Staging/swizzle is
// attn's K-tile pattern (8-row stripes, 8-block XOR, 0 conflicts).
__global__ __launch_bounds__(256) void gemm_bt2(const unsigned short* __restrict__ A,
                                                const unsigned short* __restrict__ Bt,
                                                const float* __restrict__ bias,
                                                int M, int N, int K,
                                                float* __restrict__ outF) {
  __shared__ unsigned short As[2][64 * 64];
  __shared__ unsigned short Bs[2][64 * 64];
  const int tid  = threadIdx.x;
  const int lane = tid & 63;
  const int w    = tid >> 6;
  const int m0   = blockIdx.x * 64;
  const int n0   = blockIdx.y * 64;
  const int wr   = (w >> 1) * 32;
  const int wc   = (w & 1) * 32;
  const int l16  = lane & 15;
  const int g    = lane >> 4;
  const int swz  = l16 & 7;

  f32x4 acc[2][2];
  for (int i = 0; i < 2; i++)
    for (int j = 0; j < 2; j++)
      for (int v = 0; v < 4; v++) acc[i][j][v] = 0.f;

  const int csw = (((lane & 7) ^ (lane >> 3)) & 7) * 8;
  const unsigned short* ga[2];
  const unsigned short* gb[2];
  unsigned short* la[2][2];
  unsigned short* lb[2][2];
#pragma unroll
  for (int p = 0; p < 2; p++) {
    const int r = 16 * w + 8 * p + (lane >> 3);
    ga[p] = A  + (size_t)(m0 + r) * K + csw;
    gb[p] = Bt + (size_t)(n0 + r) * K + csw;
    la[0][p] = &As[0][(16 * w + 8 * p) * 64];
    la[1][p] = &As[1][(16 * w + 8 * p) * 64];
    lb[0][p] = &Bs[0][(16 * w + 8 * p) * 64];
    lb[1][p] = &Bs[1][(16 * w + 8 * p) * 64];
  }

#pragma unroll
  for (int p = 0; p < 2; p++) { gl_lds16(ga[p], la[0][p]); gl_lds16(gb[p], lb[0][p]); }
  __syncthreads();

  for (int kt = 0; kt < K; kt += 64) {
    const int cur = (kt >> 6) & 1, nxt = cur ^ 1;
    if (kt + 64 < K) {
#pragma unroll
      for (int p = 0; p < 2; p++) {
        gl_lds16(ga[p] + kt + 64, la[nxt][p]);
        gl_lds16(gb[p] + kt + 64, lb[nxt][p]);
      }
    }
#pragma unroll
    for (int ks = 0; ks < 2; ks++) {   // k-slice: logical col-block = 4*ks+g
      bf16x8 af[2], bf[2];
#pragma unroll
      for (int i = 0; i < 2; i++)
        af[i] = *(const bf16x8*)&As[cur][(wr + i * 16 + l16) * 64 + (((ks * 4 + g) ^ swz) * 8)];
#pragma unroll
      for (int j = 0; j < 2; j++)
        bf[j] = *(const bf16x8*)&Bs[cur][(wc + j * 16 + l16) * 64 + (((ks * 4 + g) ^ swz) * 8)];
#pragma unroll
      for (int i = 0; i < 2; i++)
#pragma unroll
        for (int j = 0; j < 2; j++)
          acc[i][j] = __builtin_amdgcn_mfma_f32_16x16x32_bf16(af[i], bf[j], acc[i][j], 0, 0, 0);
    }
    __syncthreads();
  }

  const int q4 = g * 4;
#pragma unroll
  for (int i = 0; i < 2; i++)
#pragma unroll
    for (int j = 0; j < 2; j++) {
      const int mbase = m0 + wr + i * 16 + q4;
      const int n = n0 + wc + j * 16 + l16;
#pragma unroll
      for (int v = 0; v < 4; v++)
        outF[(size_t)(mbase + v) * N + n] = acc[i][j][v] + bias[n];
    }
}

// ---------------- MFMA causal flash attention, fixed-reference softmax ----------------
// R13 core (best measured): 4 waves x 16 q-rows, grid 32x32 (bh=blockIdx.x so a CU's
// 4 co-resident blocks share one head's K/V stream -- do NOT change this decode),
// register-resident P via pi k-permutation, LDS 32KB, bank conflicts = 0.
// R16: l-sum via MFMA. R18: s_setprio(1) around MFMA clusters.
__global__ __launch_bounds__(256, 4) void attn_mfma(const unsigned short* __restrict__ Qb,
                                                    const unsigned short* __restrict__ Kb,
                                                    const unsigned short* __restrict__ Vtg,
                                                    unsigned short* __restrict__ O) {
  __shared__ unsigned short Ks[2][64 * 64];   // [j][d], swizzled
  __shared__ unsigned short Vs[2][64 * 64];   // [d][j], swizzled, j pre-permuted by pi

  const int tid  = threadIdx.x;
  const int lane = tid & 63;
  const int w    = tid >> 6;
  const int g    = lane >> 4;
  const int l16  = lane & 15;
  const int bh   = blockIdx.x;
  const int tile = (int)gridDim.y - 1 - (int)blockIdx.y;   // heavy blocks first
  const int q0w  = tile * 64 + w * 16;

  const unsigned short* Qp = Qb  + (size_t)bh * Tseq * DHd;
  const unsigned short* Kp = Kb  + (size_t)bh * Tseq * DHd;
  const unsigned short* Vp = Vtg + (size_t)bh * DHd * Tseq;

  bf16x8 qf[2];
#pragma unroll
  for (int ks = 0; ks < 2; ks++)
    qf[ks] = *(const bf16x8*)&Qp[(size_t)(q0w + l16) * DHd + ks * 32 + g * 8];

  f32x4 Oacc[4];
#pragma unroll
  for (int dt = 0; dt < 4; dt++)
#pragma unroll
    for (int v = 0; v < 4; v++) Oacc[dt][v] = 0.f;

  const f32x4 FZ = {0.f, 0.f, 0.f, 0.f};     // persistent zero C-operand
  f32x4 Lacc = {0.f, 0.f, 0.f, 0.f};         // l-sums via MFMA: Lacc[v] = l[q=4g+v]
  bf16x8 onef;
  {
    union { unsigned short s[8]; bf16x8 v8; } ou;
#pragma unroll
    for (int m = 0; m < 8; m++) ou.s[m] = 0x3F80;   // bf16 1.0
    onef = ou.v8;
  }
  const int swz = l16 & 7;

  const int csw = (((lane & 7) ^ (lane >> 3)) & 7) * 8;
  const unsigned short* KgB = Kp + (size_t)(16 * w + (lane >> 3)) * DHd + csw;
  const unsigned short* VgB = Vp + (size_t)(16 * w + (lane >> 3)) * Tseq + csw;
  unsigned short* KsW[2] = { &Ks[0][16 * w * 64], &Ks[1][16 * w * 64] };
  unsigned short* VsW[2] = { &Vs[0][16 * w * 64], &Vs[1][16 * w * 64] };

  gl_lds16(KgB,             KsW[0]);
  gl_lds16(KgB + 8 * DHd,   KsW[0] + 8 * 64);
  gl_lds16(VgB,             VsW[0]);
  gl_lds16(VgB + 8 * Tseq,  VsW[0] + 8 * 64);
  __syncthreads();

  for (int c = 0; c <= tile; c++) {
    const int cur = c & 1, nxt = cur ^ 1;
    if (c < tile) {
      const size_t ko = (size_t)(c + 1) * 64 * DHd;
      const int    vo = (c + 1) * 64;
      gl_lds16(KgB + ko,            KsW[nxt]);
      gl_lds16(KgB + ko + 8 * DHd,  KsW[nxt] + 8 * 64);
      gl_lds16(VgB + vo,            VsW[nxt]);
      gl_lds16(VgB + vo + 8 * Tseq, VsW[nxt] + 8 * 64);
    }

    f32x4 st[4];
    {   // ks = 0: zero C-operand (no per-iter acc init)
      bf16x8 kf[4];
#pragma unroll
      for (int mt = 0; mt < 4; mt++)
        kf[mt] = *(const bf16x8*)&Ks[cur][(16 * mt + l16) * 64 + ((g ^ swz) * 8)];
      __builtin_amdgcn_s_setprio(1);
#pragma unroll
      for (int mt = 0; mt < 4; mt++)
        st[mt] = __builtin_amdgcn_mfma_f32_16x16x32_bf16(kf[mt], qf[0], FZ, 0, 0, 0);
      __builtin_amdgcn_s_setprio(0);
    }
    {   // ks = 1
      bf16x8 kf[4];
#pragma unroll
      for (int mt = 0; mt < 4; mt++)
        kf[mt] = *(const bf16x8*)&Ks[cur][(16 * mt + l16) * 64 + (((4 + g) ^ swz) * 8)];
      __builtin_amdgcn_s_setprio(1);
#pragma unroll
      for (int mt = 0; mt < 4; mt++)
        st[mt] = __builtin_amdgcn_mfma_f32_16x16x32_bf16(kf[mt], qf[1], st[mt], 0, 0, 0);
      __builtin_amdgcn_s_setprio(0);
    }

    if (c == tile) {
      const int qg = q0w + l16;
#pragma unroll
      for (int mt = 0; mt < 4; mt++)
#pragma unroll
        for (int v = 0; v < 4; v++)
          if ((c * 64 + 16 * mt + 4 * g + v) > qg) st[mt][v] = -1e30f;
    }

    // softmax + in-register PV A-fragment (pi-permuted k)
    unsigned int pw[2][4];
#pragma unroll
    for (int mt = 0; mt < 4; mt++) {
      float p[4];
#pragma unroll
      for (int v = 0; v < 4; v++) p[v] = __builtin_exp2f(st[mt][v]);
      pw[mt >> 1][(mt & 1) * 2 + 0] = pk_bf16(p[0], p[1]);
      pw[mt >> 1][(mt & 1) * 2 + 1] = pk_bf16(p[2], p[3]);
    }

#pragma unroll
    for (int ks = 0; ks < 2; ks++) {
      union { unsigned int u[4]; bf16x8 v8; } pu;
#pragma unroll
      for (int m = 0; m < 4; m++) pu.u[m] = pw[ks][m];
      const bf16x8 pf = pu.v8;
      bf16x8 vf[4];
#pragma unroll
      for (int dt = 0; dt < 4; dt++)
        vf[dt] = *(const bf16x8*)&Vs[cur][(16 * dt + l16) * 64 + (((4 * ks + g) ^ swz) * 8)];
      __builtin_amdgcn_s_setprio(1);
      Lacc = __builtin_amdgcn_mfma_f32_16x16x32_bf16(pf, onef, Lacc, 0, 0, 0);
#pragma unroll
      for (int dt = 0; dt < 4; dt++)
        Oacc[dt] = __builtin_amdgcn_mfma_f32_16x16x32_bf16(pf, vf[dt], Oacc[dt], 0, 0, 0);
      __builtin_amdgcn_s_setprio(0);
    }

    __syncthreads();
  }

  const float i0 = 1.f / Lacc[0], i1 = 1.f / Lacc[1];
  const float i2 = 1.f / Lacc[2], i3 = 1.f / Lacc[3];
  const int b = bh >> 4, h = bh & 15;
#pragma unroll
  for (int dt = 0; dt < 4; dt++) {
    const int d = h * DHd + 16 * dt + l16;
    const size_t r0 = (size_t)(b * Tseq + q0w + 4 * g) * Dmod + d;
    O[r0]            = f2bf(Oacc[dt][0] * i0);
    O[r0 + Dmod]     = f2bf(Oacc[dt][1] * i1);
    O[r0 + 2 * Dmod] = f2bf(Oacc[dt][2] * i2);
    O[r0 + 3 * Dmod] = f2bf(Oacc[dt][3] * i3);
  }
}

extern "C" void kernel_launch(void* const* d_in, const int* in_sizes, int n_in,
                              void* d_out, int out_size, void* d_ws, size_t ws_size,
                              hipStream_t stream) {
  (void)in_sizes; (void)n_in; (void)out_size; (void)ws_size;
  const float* x     = (const float*)d_in[0];  // [B,T,D]   fp32
  const float* w_qkv = (const float*)d_in[1];  // [D,3D]    fp32
  const float* b_qkv = (const float*)d_in[2];  // [3D]      fp32
  const float* w_out = (const float*)d_in[3];  // [D,D]     fp32
  const float* b_out = (const float*)d_in[4];  // [D]       fp32
  float* out = (float*)d_out;                  // [B,T,D]   fp32

  unsigned short* ws    = (unsigned short*)d_ws;
  unsigned short* xb    = ws;                            // [B*T, D] bf16, reused as Ob
  unsigned short* wqkvT = xb    + (size_t)4194304;       // [3D][D]
  unsigned short* woutT = wqkvT + (size_t)3072 * 1024;   // [D][D]
  unsigned short* Qb    = woutT + (size_t)1024 * 1024;   // [B,H,T,DH] (pre-scaled)
  unsigned short* Kb    = Qb + (size_t)4194304;          // [B,H,T,DH]
  unsigned short* Vt    = Kb + (size_t)4194304;          // [B,H,DH,T] (transposed, pi-permuted)
  unsigned short* Ob    = xb;  // reuse: xb dead after GEMM1

  prep<<<3072, 256, 0, stream>>>(x, w_qkv, w_out, xb, wqkvT, woutT);
  // R21: exact R19 config restored (session best 171.2us). R20's depth-2 GEMM1 was a
  // ~4us regression vs the correct within-run baseline (R19-run GEMM1 < 43us).
  gemm_bt<128, 128><<<dim3(32, 24), 256, 0, stream>>>(xb, wqkvT, b_qkv, 4096, 3072, 1024, 0,
                                                      nullptr, Qb, Kb, Vt);
  attn_mfma<<<dim3(32, 32), 256, 0, stream>>>(Qb, Kb, Vt, Ob);
  gemm_bt2<<<dim3(64, 16), 256, 0, stream>>>(Ob, woutT, b_out, 4096, 1024, 1024, out);
}

// Round 15
// 169.994 us; speedup vs baseline: 1.0388x; 1.0232x over previous
//
#include <hip/hip_runtime.h>
#include <hip/hip_bf16.h>
#include <stdint.h>

#define Bsz  2
#define Tseq 2048
#define Dmod 1024
#define Hn   16
#define DHd  64

typedef short bf16x8 __attribute__((ext_vector_type(8)));
typedef float f32x4 __attribute__((ext_vector_type(4)));

__device__ __forceinline__ float bf2f(unsigned short u) {
  union { unsigned int i; float f; } v; v.i = ((unsigned int)u) << 16; return v.f;
}
__device__ __forceinline__ unsigned short f2bf(float f) {
  union { float f; unsigned int i; } v; v.f = f;
  unsigned int r = (v.i + 0x7fffu + ((v.i >> 16) & 1u)) >> 16;
  return (unsigned short)r;
}
__device__ __forceinline__ unsigned int pk_bf16(float a, float b) {
  union { __hip_bfloat162 h; unsigned int u; } u2;
  u2.h = __float22bfloat162_rn(make_float2(a, b));
  return u2.u;
}
// async global->LDS, 16B per lane; LDS dest = wave-uniform base + lane*16
__device__ __forceinline__ void gl_lds16(const unsigned short* g, unsigned short* l) {
  __builtin_amdgcn_global_load_lds(
      (const __attribute__((address_space(1))) void*)g,
      (__attribute__((address_space(3))) void*)l, 16, 0, 0);
}

#define QSCALE 0.1803368801f   // 0.125 * log2(e), folded into Q at GEMM1 epilogue

// ---------------- fused prep: cast x -> bf16, transpose+cast w_qkv & w_out ----------------
// R18: float4 weight reads + uint4 transposed stores.
__global__ __launch_bounds__(256) void prep(const float* __restrict__ x,
                                            const float* __restrict__ w_qkv,
                                            const float* __restrict__ w_out,
                                            unsigned short* __restrict__ xb,
                                            unsigned short* __restrict__ wqkvT,
                                            unsigned short* __restrict__ woutT) {
  __shared__ unsigned short tile[64][65];
  const int blk = blockIdx.x;
  if (blk < 2048) {
    int idx = blk * 2048 + threadIdx.x * 8;
    float4 a = *(const float4*)&x[idx];
    float4 b = *(const float4*)&x[idx + 4];
    unsigned short o[8];
    o[0] = f2bf(a.x); o[1] = f2bf(a.y); o[2] = f2bf(a.z); o[3] = f2bf(a.w);
    o[4] = f2bf(b.x); o[5] = f2bf(b.y); o[6] = f2bf(b.z); o[7] = f2bf(b.w);
    *(uint4*)&xb[idx] = *(const uint4*)o;
    return;
  }
  const float* in;
  unsigned short* out;
  int K = 1024, N, k0, n0;
  if (blk < 2048 + 768) {
    int t = blk - 2048;
    in = w_qkv; out = wqkvT; N = 3072;
    n0 = (t % 48) * 64; k0 = (t / 48) * 64;
  } else {
    int t = blk - 2816;
    in = w_out; out = woutT; N = 1024;
    n0 = (t % 16) * 64; k0 = (t / 16) * 64;
  }
  for (int i = threadIdx.x * 4; i < 4096; i += 1024) {
    int r = i >> 6, c = i & 63;
    float4 f = *(const float4*)&in[(size_t)(k0 + r) * N + n0 + c];
    tile[r][c]     = f2bf(f.x);
    tile[r][c + 1] = f2bf(f.y);
    tile[r][c + 2] = f2bf(f.z);
    tile[r][c + 3] = f2bf(f.w);
  }
  __syncthreads();
  for (int i = threadIdx.x * 8; i < 4096; i += 2048) {
    int r = i >> 6, c = i & 63;
    unsigned short o[8];
#pragma unroll
    for (int j = 0; j < 8; j++) o[j] = tile[c + j][r];
    *(uint4*)&out[(size_t)(n0 + r) * K + k0 + c] = *(const uint4*)o;
  }
}

// ---------------- GEMM (BK=32 template, used by GEMM1): C = A Bt^T + bias ----------------
// STRUCTURE NOTE (R10/R17/R20 measured): 128x128, BK=32, 2-buffer, one drain-barrier
// per K-iter is this template's LOCAL OPTIMUM. Tried and regressed: 128x64 tile
// (R17), 64->128 GEMM2 (R10), 3-buffer depth-2 counted-vmcnt (R20). Cross-run GEMM1
// timings vary 43-54us with identical source -- only compare within-run.
// mode 0: scatter bf16 to Q (xQSCALE) / K [B,H,T,DH], V^T [B,H,DH,T] (sigma-permuted);
// mode 1: fp32.
template<int MT, int NT>
__global__ __launch_bounds__(256) void gemm_bt(const unsigned short* __restrict__ A,
                                               const unsigned short* __restrict__ Bt,
                                               const float* __restrict__ bias,
                                               int M, int N, int K, int mode,
                                               float* __restrict__ outF,
                                               unsigned short* __restrict__ out0,
                                               unsigned short* __restrict__ out1,
                                               unsigned short* __restrict__ out2) {
  constexpr int IT = MT / 32;   // i-tiles per wave
  constexpr int JT = NT / 32;   // j-tiles per wave
  constexpr int AP = MT / 64;   // A DMA insts per wave per kt
  constexpr int BP = NT / 64;   // B DMA insts per wave per kt
  __shared__ unsigned short As[2][MT * 32];
  __shared__ unsigned short Bs[2][NT * 32];
  const int tid  = threadIdx.x;
  const int lane = tid & 63;
  const int w    = tid >> 6;
  const int m0   = blockIdx.x * MT;
  const int n0   = blockIdx.y * NT;
  const int wr   = (w >> 1) * (MT / 2);
  const int wc   = (w & 1) * (NT / 2);

  f32x4 acc[IT][JT];
  for (int i = 0; i < IT; i++)
    for (int j = 0; j < JT; j++)
      for (int v = 0; v < 4; v++) acc[i][j][v] = 0.0f;

  const int l16  = lane & 15;
  const int g    = lane >> 4;
  const int fkey = (l16 & 3) ^ ((l16 >> 2) & 3);          // fragment swizzle key

  const int csw = (((lane & 3) ^ ((lane >> 2) & 3) ^ ((lane >> 4) & 3)) & 3) * 8;
  const unsigned short* ga[AP];
  const unsigned short* gb[BP];
  unsigned short* la[2][AP];
  unsigned short* lb[2][BP];
#pragma unroll
  for (int p = 0; p < AP; p++) {
    int r = (MT / 4) * w + 16 * p + (lane >> 2);
    ga[p] = A + (size_t)(m0 + r) * K + csw;
    la[0][p] = &As[0][((MT / 4) * w + 16 * p) * 32];
    la[1][p] = &As[1][((MT / 4) * w + 16 * p) * 32];
  }
#pragma unroll
  for (int p = 0; p < BP; p++) {
    int r = (NT / 4) * w + 16 * p + (lane >> 2);
    gb[p] = Bt + (size_t)(n0 + r) * K + csw;
    lb[0][p] = &Bs[0][((NT / 4) * w + 16 * p) * 32];
    lb[1][p] = &Bs[1][((NT / 4) * w + 16 * p) * 32];
  }

  // stage kt=0 -> buf 0
#pragma unroll
  for (int p = 0; p < AP; p++) gl_lds16(ga[p], la[0][p]);
#pragma unroll
  for (int p = 0; p < BP; p++) gl_lds16(gb[p], lb[0][p]);
  __syncthreads();

  for (int kt = 0; kt < K; kt += 32) {
    const int cur = (kt >> 5) & 1, nxt = cur ^ 1;
    if (kt + 32 < K) {   // DMA prefetch next 32-slab into the other buffer
#pragma unroll
      for (int p = 0; p < AP; p++) gl_lds16(ga[p] + kt + 32, la[nxt][p]);
#pragma unroll
      for (int p = 0; p < BP; p++) gl_lds16(gb[p] + kt + 32, lb[nxt][p]);
    }
    bf16x8 af[IT], bf[JT];
#pragma unroll
    for (int i = 0; i < IT; i++)
      af[i] = *(const bf16x8*)&As[cur][(wr + i * 16 + l16) * 32 + ((g ^ fkey) * 8)];
#pragma unroll
    for (int j = 0; j < JT; j++)
      bf[j] = *(const bf16x8*)&Bs[cur][(wc + j * 16 + l16) * 32 + ((g ^ fkey) * 8)];
#pragma unroll
    for (int i = 0; i < IT; i++)
#pragma unroll
      for (int j = 0; j < JT; j++)
        acc[i][j] = __builtin_amdgcn_mfma_f32_16x16x32_bf16(af[i], bf[j], acc[i][j], 0, 0, 0);
    __syncthreads();  // drains DMA; protects buffer swap
  }

  const int q4 = g * 4;
#pragma unroll
  for (int i = 0; i < IT; i++)
#pragma unroll
    for (int j = 0; j < JT; j++) {
      const int mbase = m0 + wr + i * 16 + q4;
      const int n = n0 + wc + j * 16 + l16;
      float vals[4];
#pragma unroll
      for (int v = 0; v < 4; v++) vals[v] = acc[i][j][v] + bias[n];
      if (mode == 1) {
#pragma unroll
        for (int v = 0; v < 4; v++)
          outF[(size_t)(mbase + v) * N + n] = vals[v];
      } else {
        const int which = n >> 10;
        const int rem = n & 1023;
        const int h = rem >> 6, dd = rem & 63;
        const int b = mbase >> 11, t = mbase & 2047;
        if (which == 2) {
          uint2 uu;
          uu.x = pk_bf16(vals[0], vals[1]);
          uu.y = pk_bf16(vals[2], vals[3]);
          // sigma = pi^-1: permute t within its 64-block so attn's PV A-fragment
          // (built lane-locally from QK^T registers) contracts matching k-positions.
          const int t2 = (t & ~63) | (t & 32) | (((t >> 2) & 3) << 3) | (((t >> 4) & 1) << 2);
          *(uint2*)&out2[((size_t)((b * Hn + h) * DHd + dd)) * Tseq + t2] = uu;
        } else if (which == 0) {
#pragma unroll
          for (int v = 0; v < 4; v++)
            out0[(size_t)((b * Hn + h) * Tseq + t + v) * DHd + dd] = f2bf(vals[v] * QSCALE);
        } else {
#pragma unroll
          for (int v = 0; v < 4; v++)
            out1[(size_t)((b * Hn + h) * Tseq + t + v) * DHd + dd] = f2bf(vals[v]);
        }
      }
    }
}

// ---------------- GEMM2: 64x64 tile, BK=64 (R19) ----------------
// Same 2-barrier dbuf structure but 64-col LDS rows: barriers halve (32->16),
// MFMA/barrier doubles (4->8), LDS 32KB keeps 4 blocks/CU. Staging/swizzle is
// attn's K-tile pattern (8-row stripes, 8-block XOR, 0 conflicts).
__global__ __launch_bounds__(256) void gemm_bt2(const unsigned short* __restrict__ A,
                                                const unsigned short* __restrict__ Bt,
                                                const float* __restrict__ bias,
                                                int M, int N, int K,
                                                float* __restrict__ outF) {
  __shared__ unsigned short As[2][64 * 64];
  __shared__ unsigned short Bs[2][64 * 64];
  const int tid  = threadIdx.x;
  const int lane = tid & 63;
  const int w    = tid >> 6;
  const int m0   = blockIdx.x * 64;
  const int n0   = blockIdx.y * 64;
  const int wr   = (w >> 1) * 32;
  const int wc   = (w & 1) * 32;
  const int l16  = lane & 15;
  const int g    = lane >> 4;
  const int swz  = l16 & 7;

  f32x4 acc[2][2];
  for (int i = 0; i < 2; i++)
    for (int j = 0; j < 2; j++)
      for (int v = 0; v < 4; v++) acc[i][j][v] = 0.f;

  const int csw = (((lane & 7) ^ (lane >> 3)) & 7) * 8;
  const unsigned short* ga[2];
  const unsigned short* gb[2];
  unsigned short* la[2][2];
  unsigned short* lb[2][2];
#pragma unroll
  for (int p = 0; p < 2; p++) {
    const int r = 16 * w + 8 * p + (lane >> 3);
    ga[p] = A  + (size_t)(m0 + r) * K + csw;
    gb[p] = Bt + (size_t)(n0 + r) * K + csw;
    la[0][p] = &As[0][(16 * w + 8 * p) * 64];
    la[1][p] = &As[1][(16 * w + 8 * p) * 64];
    lb[0][p] = &Bs[0][(16 * w + 8 * p) * 64];
    lb[1][p] = &Bs[1][(16 * w + 8 * p) * 64];
  }

#pragma unroll
  for (int p = 0; p < 2; p++) { gl_lds16(ga[p], la[0][p]); gl_lds16(gb[p], lb[0][p]); }
  __syncthreads();

  for (int kt = 0; kt < K; kt += 64) {
    const int cur = (kt >> 6) & 1, nxt = cur ^ 1;
    if (kt + 64 < K) {
#pragma unroll
      for (int p = 0; p < 2; p++) {
        gl_lds16(ga[p] + kt + 64, la[nxt][p]);
        gl_lds16(gb[p] + kt + 64, lb[nxt][p]);
      }
    }
#pragma unroll
    for (int ks = 0; ks < 2; ks++) {   // k-slice: logical col-block = 4*ks+g
      bf16x8 af[2], bf[2];
#pragma unroll
      for (int i = 0; i < 2; i++)
        af[i] = *(const bf16x8*)&As[cur][(wr + i * 16 + l16) * 64 + (((ks * 4 + g) ^ swz) * 8)];
#pragma unroll
      for (int j = 0; j < 2; j++)
        bf[j] = *(const bf16x8*)&Bs[cur][(wc + j * 16 + l16) * 64 + (((ks * 4 + g) ^ swz) * 8)];
#pragma unroll
      for (int i = 0; i < 2; i++)
#pragma unroll
        for (int j = 0; j < 2; j++)
          acc[i][j] = __builtin_amdgcn_mfma_f32_16x16x32_bf16(af[i], bf[j], acc[i][j], 0, 0, 0);
    }
    __syncthreads();
  }

  const int q4 = g * 4;
#pragma unroll
  for (int i = 0; i < 2; i++)
#pragma unroll
    for (int j = 0; j < 2; j++) {
      const int mbase = m0 + wr + i * 16 + q4;
      const int n = n0 + wc + j * 16 + l16;
#pragma unroll
      for (int v = 0; v < 4; v++)
        outF[(size_t)(mbase + v) * N + n] = acc[i][j][v] + bias[n];
    }
}

// ---------------- MFMA causal flash attention, fixed-reference softmax ----------------
// R13 core (best measured): 4 waves x 16 q-rows, grid 32x32 (bh=blockIdx.x so a CU's
// co-resident blocks share one head's K/V stream -- do NOT change this decode),
// register-resident P via pi k-permutation, LDS 32KB, bank conflicts = 0.
// R16: l-sum via MFMA. R18: s_setprio(1) around MFMA clusters.
// R22: __launch_bounds__(256,5) -- 5 blocks/CU fit exactly (5x32KB = 160KB LDS,
// VGPR 44 << 102). Grid 1024 = 4/CU avg; the 5th slot lets CUs that finish light
// (small-tile) blocks pick up extra work while heavy blocks run -> dynamic tail
// rebalancing. If LDS overhead prevents 5, HW falls back to 4 = identical behavior.
__global__ __launch_bounds__(256, 5) void attn_mfma(const unsigned short* __restrict__ Qb,
                                                    const unsigned short* __restrict__ Kb,
                                                    const unsigned short* __restrict__ Vtg,
                                                    unsigned short* __restrict__ O) {
  __shared__ unsigned short Ks[2][64 * 64];   // [j][d], swizzled
  __shared__ unsigned short Vs[2][64 * 64];   // [d][j], swizzled, j pre-permuted by pi

  const int tid  = threadIdx.x;
  const int lane = tid & 63;
  const int w    = tid >> 6;
  const int g    = lane >> 4;
  const int l16  = lane & 15;
  const int bh   = blockIdx.x;
  const int tile = (int)gridDim.y - 1 - (int)blockIdx.y;   // heavy blocks first
  const int q0w  = tile * 64 + w * 16;

  const unsigned short* Qp = Qb  + (size_t)bh * Tseq * DHd;
  const unsigned short* Kp = Kb  + (size_t)bh * Tseq * DHd;
  const unsigned short* Vp = Vtg + (size_t)bh * DHd * Tseq;

  bf16x8 qf[2];
#pragma unroll
  for (int ks = 0; ks < 2; ks++)
    qf[ks] = *(const bf16x8*)&Qp[(size_t)(q0w + l16) * DHd + ks * 32 + g * 8];

  f32x4 Oacc[4];
#pragma unroll
  for (int dt = 0; dt < 4; dt++)
#pragma unroll
    for (int v = 0; v < 4; v++) Oacc[dt][v] = 0.f;

  const f32x4 FZ = {0.f, 0.f, 0.f, 0.f};     // persistent zero C-operand
  f32x4 Lacc = {0.f, 0.f, 0.f, 0.f};         // l-sums via MFMA: Lacc[v] = l[q=4g+v]
  bf16x8 onef;
  {
    union { unsigned short s[8]; bf16x8 v8; } ou;
#pragma unroll
    for (int m = 0; m < 8; m++) ou.s[m] = 0x3F80;   // bf16 1.0
    onef = ou.v8;
  }
  const int swz = l16 & 7;

  const int csw = (((lane & 7) ^ (lane >> 3)) & 7) * 8;
  const unsigned short* KgB = Kp + (size_t)(16 * w + (lane >> 3)) * DHd + csw;
  const unsigned short* VgB = Vp + (size_t)(16 * w + (lane >> 3)) * Tseq + csw;
  unsigned short* KsW[2] = { &Ks[0][16 * w * 64], &Ks[1][16 * w * 64] };
  unsigned short* VsW[2] = { &Vs[0][16 * w * 64], &Vs[1][16 * w * 64] };

  gl_lds16(KgB,             KsW[0]);
  gl_lds16(KgB + 8 * DHd,   KsW[0] + 8 * 64);
  gl_lds16(VgB,             VsW[0]);
  gl_lds16(VgB + 8 * Tseq,  VsW[0] + 8 * 64);
  __syncthreads();

  for (int c = 0; c <= tile; c++) {
    const int cur = c & 1, nxt = cur ^ 1;
    if (c < tile) {
      const size_t ko = (size_t)(c + 1) * 64 * DHd;
      const int    vo = (c + 1) * 64;
      gl_lds16(KgB + ko,            KsW[nxt]);
      gl_lds16(KgB + ko + 8 * DHd,  KsW[nxt] + 8 * 64);
      gl_lds16(VgB + vo,            VsW[nxt]);
      gl_lds16(VgB + vo + 8 * Tseq, VsW[nxt] + 8 * 64);
    }

    f32x4 st[4];
    {   // ks = 0: zero C-operand (no per-iter acc init)
      bf16x8 kf[4];
#pragma unroll
      for (int mt = 0; mt < 4; mt++)
        kf[mt] = *(const bf16x8*)&Ks[cur][(16 * mt + l16) * 64 + ((g ^ swz) * 8)];
      __builtin_amdgcn_s_setprio(1);
#pragma unroll
      for (int mt = 0; mt < 4; mt++)
        st[mt] = __builtin_amdgcn_mfma_f32_16x16x32_bf16(kf[mt], qf[0], FZ, 0, 0, 0);
      __builtin_amdgcn_s_setprio(0);
    }
    {   // ks = 1
      bf16x8 kf[4];
#pragma unroll
      for (int mt = 0; mt < 4; mt++)
        kf[mt] = *(const bf16x8*)&Ks[cur][(16 * mt + l16) * 64 + (((4 + g) ^ swz) * 8)];
      __builtin_amdgcn_s_setprio(1);
#pragma unroll
      for (int mt = 0; mt < 4; mt++)
        st[mt] = __builtin_amdgcn_mfma_f32_16x16x32_bf16(kf[mt], qf[1], st[mt], 0, 0, 0);
      __builtin_amdgcn_s_setprio(0);
    }

    if (c == tile) {
      const int qg = q0w + l16;
#pragma unroll
      for (int mt = 0; mt < 4; mt++)
#pragma unroll
        for (int v = 0; v < 4; v++)
          if ((c * 64 + 16 * mt + 4 * g + v) > qg) st[mt][v] = -1e30f;
    }

    // softmax + in-register PV A-fragment (pi-permuted k)
    unsigned int pw[2][4];
#pragma unroll
    for (int mt = 0; mt < 4; mt++) {
      float p[4];
#pragma unroll
      for (int v = 0; v < 4; v++) p[v] = __builtin_exp2f(st[mt][v]);
      pw[mt >> 1][(mt & 1) * 2 + 0] = pk_bf16(p[0], p[1]);
      pw[mt >> 1][(mt & 1) * 2 + 1] = pk_bf16(p[2], p[3]);
    }

#pragma unroll
    for (int ks = 0; ks < 2; ks++) {
      union { unsigned int u[4]; bf16x8 v8; } pu;
#pragma unroll
      for (int m = 0; m < 4; m++) pu.u[m] = pw[ks][m];
      const bf16x8 pf = pu.v8;
      bf16x8 vf[4];
#pragma unroll
      for (int dt = 0; dt < 4; dt++)
        vf[dt] = *(const bf16x8*)&Vs[cur][(16 * dt + l16) * 64 + (((4 * ks + g) ^ swz) * 8)];
      __builtin_amdgcn_s_setprio(1);
      Lacc = __builtin_amdgcn_mfma_f32_16x16x32_bf16(pf, onef, Lacc, 0, 0, 0);
#pragma unroll
      for (int dt = 0; dt < 4; dt++)
        Oacc[dt] = __builtin_amdgcn_mfma_f32_16x16x32_bf16(pf, vf[dt], Oacc[dt], 0, 0, 0);
      __builtin_amdgcn_s_setprio(0);
    }

    __syncthreads();
  }

  const float i0 = 1.f / Lacc[0], i1 = 1.f / Lacc[1];
  const float i2 = 1.f / Lacc[2], i3 = 1.f / Lacc[3];
  const int b = bh >> 4, h = bh & 15;
#pragma unroll
  for (int dt = 0; dt < 4; dt++) {
    const int d = h * DHd + 16 * dt + l16;
    const size_t r0 = (size_t)(b * Tseq + q0w + 4 * g) * Dmod + d;
    O[r0]            = f2bf(Oacc[dt][0] * i0);
    O[r0 + Dmod]     = f2bf(Oacc[dt][1] * i1);
    O[r0 + 2 * Dmod] = f2bf(Oacc[dt][2] * i2);
    O[r0 + 3 * Dmod] = f2bf(Oacc[dt][3] * i3);
  }
}

extern "C" void kernel_launch(void* const* d_in, const int* in_sizes, int n_in,
                              void* d_out, int out_size, void* d_ws, size_t ws_size,
                              hipStream_t stream) {
  (void)in_sizes; (void)n_in; (void)out_size; (void)ws_size;
  const float* x     = (const float*)d_in[0];  // [B,T,D]   fp32
  const float* w_qkv = (const float*)d_in[1];  // [D,3D]    fp32
  const float* b_qkv = (const float*)d_in[2];  // [3D]      fp32
  const float* w_out = (const float*)d_in[3];  // [D,D]     fp32
  const float* b_out = (const float*)d_in[4];  // [D]       fp32
  float* out = (float*)d_out;                  // [B,T,D]   fp32

  unsigned short* ws    = (unsigned short*)d_ws;
  unsigned short* xb    = ws;                            // [B*T, D] bf16, reused as Ob
  unsigned short* wqkvT = xb    + (size_t)4194304;       // [3D][D]
  unsigned short* woutT = wqkvT + (size_t)3072 * 1024;   // [D][D]
  unsigned short* Qb    = woutT + (size_t)1024 * 1024;   // [B,H,T,DH] (pre-scaled)
  unsigned short* Kb    = Qb + (size_t)4194304;          // [B,H,T,DH]
  unsigned short* Vt    = Kb + (size_t)4194304;          // [B,H,DH,T] (transposed, pi-permuted)
  unsigned short* Ob    = xb;  // reuse: xb dead after GEMM1

  prep<<<3072, 256, 0, stream>>>(x, w_qkv, w_out, xb, wqkvT, woutT);
  gemm_bt<128, 128><<<dim3(32, 24), 256, 0, stream>>>(xb, wqkvT, b_qkv, 4096, 3072, 1024, 0,
                                                      nullptr, Qb, Kb, Vt);
  // R22: attn with 5-blocks/CU capacity for dynamic tail rebalancing
  attn_mfma<<<dim3(32, 32), 256, 0, stream>>>(Qb, Kb, Vt, Ob);
  gemm_bt2<<<dim3(64, 16), 256, 0, stream>>>(Ob, woutT, b_out, 4096, 1024, 1024, out);
}

// Round 16
// 169.656 us; speedup vs baseline: 1.0409x; 1.0020x over previous
//
#include <hip/hip_runtime.h>
#include <hip/hip_bf16.h>
#include <stdint.h>

#define Bsz  2
#define Tseq 2048
#define Dmod 1024
#define Hn   16
#define DHd  64

typedef short bf16x8 __attribute__((ext_vector_type(8)));
typedef float f32x4 __attribute__((ext_vector_type(4)));

__device__ __forceinline__ float bf2f(unsigned short u) {
  union { unsigned int i; float f; } v; v.i = ((unsigned int)u) << 16; return v.f;
}
__device__ __forceinline__ unsigned short f2bf(float f) {
  union { float f; unsigned int i; } v; v.f = f;
  unsigned int r = (v.i + 0x7fffu + ((v.i >> 16) & 1u)) >> 16;
  return (unsigned short)r;
}
__device__ __forceinline__ unsigned int pk_bf16(float a, float b) {
  union { __hip_bfloat162 h; unsigned int u; } u2;
  u2.h = __float22bfloat162_rn(make_float2(a, b));
  return u2.u;
}
// async global->LDS, 16B per lane; LDS dest = wave-uniform base + lane*16
__device__ __forceinline__ void gl_lds16(const unsigned short* g, unsigned short* l) {
  __builtin_amdgcn_global_load_lds(
      (const __attribute__((address_space(1))) void*)g,
      (__attribute__((address_space(3))) void*)l, 16, 0, 0);
}

#define QSCALE 0.1803368801f   // 0.125 * log2(e), folded into Q at GEMM1 epilogue

// ---------------- fused prep: cast x -> bf16, transpose+cast w_qkv & w_out ----------------
// R18: float4 weight reads + uint4 transposed stores.
__global__ __launch_bounds__(256) void prep(const float* __restrict__ x,
                                            const float* __restrict__ w_qkv,
                                            const float* __restrict__ w_out,
                                            unsigned short* __restrict__ xb,
                                            unsigned short* __restrict__ wqkvT,
                                            unsigned short* __restrict__ woutT) {
  __shared__ unsigned short tile[64][65];
  const int blk = blockIdx.x;
  if (blk < 2048) {
    int idx = blk * 2048 + threadIdx.x * 8;
    float4 a = *(const float4*)&x[idx];
    float4 b = *(const float4*)&x[idx + 4];
    unsigned short o[8];
    o[0] = f2bf(a.x); o[1] = f2bf(a.y); o[2] = f2bf(a.z); o[3] = f2bf(a.w);
    o[4] = f2bf(b.x); o[5] = f2bf(b.y); o[6] = f2bf(b.z); o[7] = f2bf(b.w);
    *(uint4*)&xb[idx] = *(const uint4*)o;
    return;
  }
  const float* in;
  unsigned short* out;
  int K = 1024, N, k0, n0;
  if (blk < 2048 + 768) {
    int t = blk - 2048;
    in = w_qkv; out = wqkvT; N = 3072;
    n0 = (t % 48) * 64; k0 = (t / 48) * 64;
  } else {
    int t = blk - 2816;
    in = w_out; out = woutT; N = 1024;
    n0 = (t % 16) * 64; k0 = (t / 16) * 64;
  }
  for (int i = threadIdx.x * 4; i < 4096; i += 1024) {
    int r = i >> 6, c = i & 63;
    float4 f = *(const float4*)&in[(size_t)(k0 + r) * N + n0 + c];
    tile[r][c]     = f2bf(f.x);
    tile[r][c + 1] = f2bf(f.y);
    tile[r][c + 2] = f2bf(f.z);
    tile[r][c + 3] = f2bf(f.w);
  }
  __syncthreads();
  for (int i = threadIdx.x * 8; i < 4096; i += 2048) {
    int r = i >> 6, c = i & 63;
    unsigned short o[8];
#pragma unroll
    for (int j = 0; j < 8; j++) o[j] = tile[c + j][r];
    *(uint4*)&out[(size_t)(n0 + r) * K + k0 + c] = *(const uint4*)o;
  }
}

// ---------------- GEMM (BK=32 template, used by GEMM1): C = A Bt^T + bias ----------------
// STRUCTURE NOTE (R10/R17/R20 measured): 128x128, BK=32, 2-buffer, one drain-barrier
// per K-iter is this template's LOCAL OPTIMUM. Tried and regressed: 128x64 tile
// (R17), 64->128 GEMM2 (R10), 3-buffer depth-2 counted-vmcnt (R20). Cross-run GEMM1
// timings vary 43-54us with identical source -- only compare within-run.
// mode 0: scatter bf16 to Q (xQSCALE) / K [B,H,T,DH], V^T [B,H,DH,T] (sigma-permuted);
// mode 1: fp32.
template<int MT, int NT>
__global__ __launch_bounds__(256) void gemm_bt(const unsigned short* __restrict__ A,
                                               const unsigned short* __restrict__ Bt,
                                               const float* __restrict__ bias,
                                               int M, int N, int K, int mode,
                                               float* __restrict__ outF,
                                               unsigned short* __restrict__ out0,
                                               unsigned short* __restrict__ out1,
                                               unsigned short* __restrict__ out2) {
  constexpr int IT = MT / 32;   // i-tiles per wave
  constexpr int JT = NT / 32;   // j-tiles per wave
  constexpr int AP = MT / 64;   // A DMA insts per wave per kt
  constexpr int BP = NT / 64;   // B DMA insts per wave per kt
  __shared__ unsigned short As[2][MT * 32];
  __shared__ unsigned short Bs[2][NT * 32];
  const int tid  = threadIdx.x;
  const int lane = tid & 63;
  const int w    = tid >> 6;
  const int m0   = blockIdx.x * MT;
  const int n0   = blockIdx.y * NT;
  const int wr   = (w >> 1) * (MT / 2);
  const int wc   = (w & 1) * (NT / 2);

  f32x4 acc[IT][JT];
  for (int i = 0; i < IT; i++)
    for (int j = 0; j < JT; j++)
      for (int v = 0; v < 4; v++) acc[i][j][v] = 0.0f;

  const int l16  = lane & 15;
  const int g    = lane >> 4;
  const int fkey = (l16 & 3) ^ ((l16 >> 2) & 3);          // fragment swizzle key

  const int csw = (((lane & 3) ^ ((lane >> 2) & 3) ^ ((lane >> 4) & 3)) & 3) * 8;
  const unsigned short* ga[AP];
  const unsigned short* gb[BP];
  unsigned short* la[2][AP];
  unsigned short* lb[2][BP];
#pragma unroll
  for (int p = 0; p < AP; p++) {
    int r = (MT / 4) * w + 16 * p + (lane >> 2);
    ga[p] = A + (size_t)(m0 + r) * K + csw;
    la[0][p] = &As[0][((MT / 4) * w + 16 * p) * 32];
    la[1][p] = &As[1][((MT / 4) * w + 16 * p) * 32];
  }
#pragma unroll
  for (int p = 0; p < BP; p++) {
    int r = (NT / 4) * w + 16 * p + (lane >> 2);
    gb[p] = Bt + (size_t)(n0 + r) * K + csw;
    lb[0][p] = &Bs[0][((NT / 4) * w + 16 * p) * 32];
    lb[1][p] = &Bs[1][((NT / 4) * w + 16 * p) * 32];
  }

  // stage kt=0 -> buf 0
#pragma unroll
  for (int p = 0; p < AP; p++) gl_lds16(ga[p], la[0][p]);
#pragma unroll
  for (int p = 0; p < BP; p++) gl_lds16(gb[p], lb[0][p]);
  __syncthreads();

  for (int kt = 0; kt < K; kt += 32) {
    const int cur = (kt >> 5) & 1, nxt = cur ^ 1;
    if (kt + 32 < K) {   // DMA prefetch next 32-slab into the other buffer
#pragma unroll
      for (int p = 0; p < AP; p++) gl_lds16(ga[p] + kt + 32, la[nxt][p]);
#pragma unroll
      for (int p = 0; p < BP; p++) gl_lds16(gb[p] + kt + 32, lb[nxt][p]);
    }
    bf16x8 af[IT], bf[JT];
#pragma unroll
    for (int i = 0; i < IT; i++)
      af[i] = *(const bf16x8*)&As[cur][(wr + i * 16 + l16) * 32 + ((g ^ fkey) * 8)];
#pragma unroll
    for (int j = 0; j < JT; j++)
      bf[j] = *(const bf16x8*)&Bs[cur][(wc + j * 16 + l16) * 32 + ((g ^ fkey) * 8)];
#pragma unroll
    for (int i = 0; i < IT; i++)
#pragma unroll
      for (int j = 0; j < JT; j++)
        acc[i][j] = __builtin_amdgcn_mfma_f32_16x16x32_bf16(af[i], bf[j], acc[i][j], 0, 0, 0);
    __syncthreads();  // drains DMA; protects buffer swap
  }

  const int q4 = g * 4;
#pragma unroll
  for (int i = 0; i < IT; i++)
#pragma unroll
    for (int j = 0; j < JT; j++) {
      const int mbase = m0 + wr + i * 16 + q4;
      const int n = n0 + wc + j * 16 + l16;
      float vals[4];
#pragma unroll
      for (int v = 0; v < 4; v++) vals[v] = acc[i][j][v] + bias[n];
      if (mode == 1) {
#pragma unroll
        for (int v = 0; v < 4; v++)
          outF[(size_t)(mbase + v) * N + n] = vals[v];
      } else {
        const int which = n >> 10;
        const int rem = n & 1023;
        const int h = rem >> 6, dd = rem & 63;
        const int b = mbase >> 11, t = mbase & 2047;
        if (which == 2) {
          uint2 uu;
          uu.x = pk_bf16(vals[0], vals[1]);
          uu.y = pk_bf16(vals[2], vals[3]);
          // sigma = pi^-1: permute t within its 64-block so attn's PV A-fragment
          // (built lane-locally from QK^T registers) contracts matching k-positions.
          const int t2 = (t & ~63) | (t & 32) | (((t >> 2) & 3) << 3) | (((t >> 4) & 1) << 2);
          *(uint2*)&out2[((size_t)((b * Hn + h) * DHd + dd)) * Tseq + t2] = uu;
        } else if (which == 0) {
#pragma unroll
          for (int v = 0; v < 4; v++)
            out0[(size_t)((b * Hn + h) * Tseq + t + v) * DHd + dd] = f2bf(vals[v] * QSCALE);
        } else {
#pragma unroll
          for (int v = 0; v < 4; v++)
            out1[(size_t)((b * Hn + h) * Tseq + t + v) * DHd + dd] = f2bf(vals[v]);
        }
      }
    }
}

// ---------------- GEMM2: 64x64 tile, BK=64 (R19) ----------------
// Same 2-barrier dbuf structure but 64-col LDS rows: barriers halve (32->16),
// MFMA/barrier doubles (4->8), LDS 32KB keeps 4 blocks/CU. Staging/swizzle is
// attn's K-tile pattern (8-row stripes, 8-block XOR, 0 conflicts).
// R23: __launch_bounds__(256,5) -- same tail-slot hint as attn (R22, -4us there):
// 5x32KB = 160KB fits exactly; VGPR 44 << 102 cap; if the HW can't place a 5th
// block, behavior is identical (bounded downside).
__global__ __launch_bounds__(256, 5) void gemm_bt2(const unsigned short* __restrict__ A,
                                                   const unsigned short* __restrict__ Bt,
                                                   const float* __restrict__ bias,
                                                   int M, int N, int K,
                                                   float* __restrict__ outF) {
  __shared__ unsigned short As[2][64 * 64];
  __shared__ unsigned short Bs[2][64 * 64];
  const int tid  = threadIdx.x;
  const int lane = tid & 63;
  const int w    = tid >> 6;
  const int m0   = blockIdx.x * 64;
  const int n0   = blockIdx.y * 64;
  const int wr   = (w >> 1) * 32;
  const int wc   = (w & 1) * 32;
  const int l16  = lane & 15;
  const int g    = lane >> 4;
  const int swz  = l16 & 7;

  f32x4 acc[2][2];
  for (int i = 0; i < 2; i++)
    for (int j = 0; j < 2; j++)
      for (int v = 0; v < 4; v++) acc[i][j][v] = 0.f;

  const int csw = (((lane & 7) ^ (lane >> 3)) & 7) * 8;
  const unsigned short* ga[2];
  const unsigned short* gb[2];
  unsigned short* la[2][2];
  unsigned short* lb[2][2];
#pragma unroll
  for (int p = 0; p < 2; p++) {
    const int r = 16 * w + 8 * p + (lane >> 3);
    ga[p] = A  + (size_t)(m0 + r) * K + csw;
    gb[p] = Bt + (size_t)(n0 + r) * K + csw;
    la[0][p] = &As[0][(16 * w + 8 * p) * 64];
    la[1][p] = &As[1][(16 * w + 8 * p) * 64];
    lb[0][p] = &Bs[0][(16 * w + 8 * p) * 64];
    lb[1][p] = &Bs[1][(16 * w + 8 * p) * 64];
  }

#pragma unroll
  for (int p = 0; p < 2; p++) { gl_lds16(ga[p], la[0][p]); gl_lds16(gb[p], lb[0][p]); }
  __syncthreads();

  for (int kt = 0; kt < K; kt += 64) {
    const int cur = (kt >> 6) & 1, nxt = cur ^ 1;
    if (kt + 64 < K) {
#pragma unroll
      for (int p = 0; p < 2; p++) {
        gl_lds16(ga[p] + kt + 64, la[nxt][p]);
        gl_lds16(gb[p] + kt + 64, lb[nxt][p]);
      }
    }
#pragma unroll
    for (int ks = 0; ks < 2; ks++) {   // k-slice: logical col-block = 4*ks+g
      bf16x8 af[2], bf[2];
#pragma unroll
      for (int i = 0; i < 2; i++)
        af[i] = *(const bf16x8*)&As[cur][(wr + i * 16 + l16) * 64 + (((ks * 4 + g) ^ swz) * 8)];
#pragma unroll
      for (int j = 0; j < 2; j++)
        bf[j] = *(const bf16x8*)&Bs[cur][(wc + j * 16 + l16) * 64 + (((ks * 4 + g) ^ swz) * 8)];
#pragma unroll
      for (int i = 0; i < 2; i++)
#pragma unroll
        for (int j = 0; j < 2; j++)
          acc[i][j] = __builtin_amdgcn_mfma_f32_16x16x32_bf16(af[i], bf[j], acc[i][j], 0, 0, 0);
    }
    __syncthreads();
  }

  const int q4 = g * 4;
#pragma unroll
  for (int i = 0; i < 2; i++)
#pragma unroll
    for (int j = 0; j < 2; j++) {
      const int mbase = m0 + wr + i * 16 + q4;
      const int n = n0 + wc + j * 16 + l16;
#pragma unroll
      for (int v = 0; v < 4; v++)
        outF[(size_t)(mbase + v) * N + n] = acc[i][j][v] + bias[n];
    }
}

// ---------------- MFMA causal flash attention, fixed-reference softmax ----------------
// R13 core (best measured): 4 waves x 16 q-rows, grid 32x32 (bh=blockIdx.x so a CU's
// co-resident blocks share one head's K/V stream -- do NOT change this decode),
// register-resident P via pi k-permutation, LDS 32KB, bank conflicts = 0.
// R16: l-sum via MFMA. R18: s_setprio(1) around MFMA clusters.
// R22: __launch_bounds__(256,5) -- dynamic tail rebalancing (173.9 -> 170.0us).
__global__ __launch_bounds__(256, 5) void attn_mfma(const unsigned short* __restrict__ Qb,
                                                    const unsigned short* __restrict__ Kb,
                                                    const unsigned short* __restrict__ Vtg,
                                                    unsigned short* __restrict__ O) {
  __shared__ unsigned short Ks[2][64 * 64];   // [j][d], swizzled
  __shared__ unsigned short Vs[2][64 * 64];   // [d][j], swizzled, j pre-permuted by pi

  const int tid  = threadIdx.x;
  const int lane = tid & 63;
  const int w    = tid >> 6;
  const int g    = lane >> 4;
  const int l16  = lane & 15;
  const int bh   = blockIdx.x;
  const int tile = (int)gridDim.y - 1 - (int)blockIdx.y;   // heavy blocks first
  const int q0w  = tile * 64 + w * 16;

  const unsigned short* Qp = Qb  + (size_t)bh * Tseq * DHd;
  const unsigned short* Kp = Kb  + (size_t)bh * Tseq * DHd;
  const unsigned short* Vp = Vtg + (size_t)bh * DHd * Tseq;

  bf16x8 qf[2];
#pragma unroll
  for (int ks = 0; ks < 2; ks++)
    qf[ks] = *(const bf16x8*)&Qp[(size_t)(q0w + l16) * DHd + ks * 32 + g * 8];

  f32x4 Oacc[4];
#pragma unroll
  for (int dt = 0; dt < 4; dt++)
#pragma unroll
    for (int v = 0; v < 4; v++) Oacc[dt][v] = 0.f;

  const f32x4 FZ = {0.f, 0.f, 0.f, 0.f};     // persistent zero C-operand
  f32x4 Lacc = {0.f, 0.f, 0.f, 0.f};         // l-sums via MFMA: Lacc[v] = l[q=4g+v]
  bf16x8 onef;
  {
    union { unsigned short s[8]; bf16x8 v8; } ou;
#pragma unroll
    for (int m = 0; m < 8; m++) ou.s[m] = 0x3F80;   // bf16 1.0
    onef = ou.v8;
  }
  const int swz = l16 & 7;

  const int csw = (((lane & 7) ^ (lane >> 3)) & 7) * 8;
  const unsigned short* KgB = Kp + (size_t)(16 * w + (lane >> 3)) * DHd + csw;
  const unsigned short* VgB = Vp + (size_t)(16 * w + (lane >> 3)) * Tseq + csw;
  unsigned short* KsW[2] = { &Ks[0][16 * w * 64], &Ks[1][16 * w * 64] };
  unsigned short* VsW[2] = { &Vs[0][16 * w * 64], &Vs[1][16 * w * 64] };

  gl_lds16(KgB,             KsW[0]);
  gl_lds16(KgB + 8 * DHd,   KsW[0] + 8 * 64);
  gl_lds16(VgB,             VsW[0]);
  gl_lds16(VgB + 8 * Tseq,  VsW[0] + 8 * 64);
  __syncthreads();

  for (int c = 0; c <= tile; c++) {
    const int cur = c & 1, nxt = cur ^ 1;
    if (c < tile) {
      const size_t ko = (size_t)(c + 1) * 64 * DHd;
      const int    vo = (c + 1) * 64;
      gl_lds16(KgB + ko,            KsW[nxt]);
      gl_lds16(KgB + ko + 8 * DHd,  KsW[nxt] + 8 * 64);
      gl_lds16(VgB + vo,            VsW[nxt]);
      gl_lds16(VgB + vo + 8 * Tseq, VsW[nxt] + 8 * 64);
    }

    f32x4 st[4];
    {   // ks = 0: zero C-operand (no per-iter acc init)
      bf16x8 kf[4];
#pragma unroll
      for (int mt = 0; mt < 4; mt++)
        kf[mt] = *(const bf16x8*)&Ks[cur][(16 * mt + l16) * 64 + ((g ^ swz) * 8)];
      __builtin_amdgcn_s_setprio(1);
#pragma unroll
      for (int mt = 0; mt < 4; mt++)
        st[mt] = __builtin_amdgcn_mfma_f32_16x16x32_bf16(kf[mt], qf[0], FZ, 0, 0, 0);
      __builtin_amdgcn_s_setprio(0);
    }
    {   // ks = 1
      bf16x8 kf[4];
#pragma unroll
      for (int mt = 0; mt < 4; mt++)
        kf[mt] = *(const bf16x8*)&Ks[cur][(16 * mt + l16) * 64 + (((4 + g) ^ swz) * 8)];
      __builtin_amdgcn_s_setprio(1);
#pragma unroll
      for (int mt = 0; mt < 4; mt++)
        st[mt] = __builtin_amdgcn_mfma_f32_16x16x32_bf16(kf[mt], qf[1], st[mt], 0, 0, 0);
      __builtin_amdgcn_s_setprio(0);
    }

    if (c == tile) {
      const int qg = q0w + l16;
#pragma unroll
      for (int mt = 0; mt < 4; mt++)
#pragma unroll
        for (int v = 0; v < 4; v++)
          if ((c * 64 + 16 * mt + 4 * g + v) > qg) st[mt][v] = -1e30f;
    }

    // softmax + in-register PV A-fragment (pi-permuted k)
    unsigned int pw[2][4];
#pragma unroll
    for (int mt = 0; mt < 4; mt++) {
      float p[4];
#pragma unroll
      for (int v = 0; v < 4; v++) p[v] = __builtin_exp2f(st[mt][v]);
      pw[mt >> 1][(mt & 1) * 2 + 0] = pk_bf16(p[0], p[1]);
      pw[mt >> 1][(mt & 1) * 2 + 1] = pk_bf16(p[2], p[3]);
    }

#pragma unroll
    for (int ks = 0; ks < 2; ks++) {
      union { unsigned int u[4]; bf16x8 v8; } pu;
#pragma unroll
      for (int m = 0; m < 4; m++) pu.u[m] = pw[ks][m];
      const bf16x8 pf = pu.v8;
      bf16x8 vf[4];
#pragma unroll
      for (int dt = 0; dt < 4; dt++)
        vf[dt] = *(const bf16x8*)&Vs[cur][(16 * dt + l16) * 64 + (((4 * ks + g) ^ swz) * 8)];
      __builtin_amdgcn_s_setprio(1);
      Lacc = __builtin_amdgcn_mfma_f32_16x16x32_bf16(pf, onef, Lacc, 0, 0, 0);
#pragma unroll
      for (int dt = 0; dt < 4; dt++)
        Oacc[dt] = __builtin_amdgcn_mfma_f32_16x16x32_bf16(pf, vf[dt], Oacc[dt], 0, 0, 0);
      __builtin_amdgcn_s_setprio(0);
    }

    __syncthreads();
  }

  const float i0 = 1.f / Lacc[0], i1 = 1.f / Lacc[1];
  const float i2 = 1.f / Lacc[2], i3 = 1.f / Lacc[3];
  const int b = bh >> 4, h = bh & 15;
#pragma unroll
  for (int dt = 0; dt < 4; dt++) {
    const int d = h * DHd + 16 * dt + l16;
    const size_t r0 = (size_t)(b * Tseq + q0w + 4 * g) * Dmod + d;
    O[r0]            = f2bf(Oacc[dt][0] * i0);
    O[r0 + Dmod]     = f2bf(Oacc[dt][1] * i1);
    O[r0 + 2 * Dmod] = f2bf(Oacc[dt][2] * i2);
    O[r0 + 3 * Dmod] = f2bf(Oacc[dt][3] * i3);
  }
}

extern "C" void kernel_launch(void* const* d_in, const int* in_sizes, int n_in,
                              void* d_out, int out_size, void* d_ws, size_t ws_size,
                              hipStream_t stream) {
  (void)in_sizes; (void)n_in; (void)out_size; (void)ws_size;
  const float* x     = (const float*)d_in[0];  // [B,T,D]   fp32
  const float* w_qkv = (const float*)d_in[1];  // [D,3D]    fp32
  const float* b_qkv = (const float*)d_in[2];  // [3D]      fp32
  const float* w_out = (const float*)d_in[3];  // [D,D]     fp32
  const float* b_out = (const float*)d_in[4];  // [D]       fp32
  float* out = (float*)d_out;                  // [B,T,D]   fp32

  unsigned short* ws    = (unsigned short*)d_ws;
  unsigned short* xb    = ws;                            // [B*T, D] bf16, reused as Ob
  unsigned short* wqkvT = xb    + (size_t)4194304;       // [3D][D]
  unsigned short* woutT = wqkvT + (size_t)3072 * 1024;   // [D][D]
  unsigned short* Qb    = woutT + (size_t)1024 * 1024;   // [B,H,T,DH] (pre-scaled)
  unsigned short* Kb    = Qb + (size_t)4194304;          // [B,H,T,DH]
  unsigned short* Vt    = Kb + (size_t)4194304;          // [B,H,DH,T] (transposed, pi-permuted)
  unsigned short* Ob    = xb;  // reuse: xb dead after GEMM1

  prep<<<3072, 256, 0, stream>>>(x, w_qkv, w_out, xb, wqkvT, woutT);
  gemm_bt<128, 128><<<dim3(32, 24), 256, 0, stream>>>(xb, wqkvT, b_qkv, 4096, 3072, 1024, 0,
                                                      nullptr, Qb, Kb, Vt);
  attn_mfma<<<dim3(32, 32), 256, 0, stream>>>(Qb, Kb, Vt, Ob);
  // R23: GEMM2 with the 5-block/CU tail-slot hint (R22's attn win, same mechanism)
  gemm_bt2<<<dim3(64, 16), 256, 0, stream>>>(Ob, woutT, b_out, 4096, 1024, 1024, out);
}